// Round 1
// baseline (1143.008 us; speedup 1.0000x reference)
//
#include <hip/hip_runtime.h>
#include <cstdint>
#include <cstddef>

// LSTM cell: B=1024, D_IN=D_H=4096, fp32 in/out.
// z = [x|h] @ [[W],[U]] via bf16 MFMA. Bt[n'][k] gate-interleaved:
// n' = (hc>>4)*64 + gate*16 + (hc&15)  ->  per-block BN=64 slab holds all 4
// gates for 16 h-cols; GEMM epilogue computes gates/c/h in-register.
// This rev: (1) chunk-major LDS image in lstm_gemm (kills 8-way ds_read_b128
// bank conflicts; SQ_LDS_BANK_CONFLICT was 2.5e7/dispatch), (2) conv_w3 =
// padded fp32 LDS transpose (old conv_w2 ran ~1.6 TB/s from 8-way LDS
// conflicts on both phases), (3) grid swapped to (N,M) so the 2 M-blocks of
// one Bt slab land on the same XCD.

typedef __bf16 bf16;
typedef __bf16 bf16x8 __attribute__((ext_vector_type(8)));
typedef __bf16 bf16x4 __attribute__((ext_vector_type(4)));
typedef float f32x4 __attribute__((ext_vector_type(4)));

static constexpr int Bn = 1024;   // batch
static constexpr int DH = 4096;
static constexpr int K  = 8192;   // 2*DH
static constexpr int BM = 512, BN = 64, BK = 32;

__device__ __forceinline__ void load_lds16(const void* g, void* l) {
  __builtin_amdgcn_global_load_lds(
      (const __attribute__((address_space(1))) unsigned int*)g,
      (__attribute__((address_space(3))) unsigned int*)l, 16, 0, 0);
}

// ---------------- kernel 1: pack A = [x | h_prev] -> bf16 [Bn][K] ------------
__global__ void pack_A(const float* __restrict__ x, const float* __restrict__ h,
                       bf16* __restrict__ A) {
  int idx4 = blockIdx.x * blockDim.x + threadIdx.x;   // one float4 position
  int b = idx4 >> 11;           // 2048 float4 per K-row
  int q = idx4 & 2047;
  int k = q << 2;
  const float* src = (k < DH) ? (x + (size_t)b * DH + k)
                              : (h + (size_t)b * DH + (k - DH));
  float4 v = *(const float4*)src;
  bf16x4 o;
  o[0] = (bf16)v.x; o[1] = (bf16)v.y; o[2] = (bf16)v.z; o[3] = (bf16)v.w;
  *(bf16x4*)(A + (size_t)idx4 * 4) = o;
}

// ---- kernel 2: transpose+convert weights -> gate-interleaved Bt[n'][k] ------
// Classic padded-LDS fp32 transpose: tile[64n][65k-stride]. Stride 65 gives a
// 1-dword bank rotation per n-row:
//   phase-1 writes (scattered b32): bank = 4c + j + kk -> 2-way per quarter.
//   phase-2 reads (8x b32 along k): bank = nl + 8u + e  -> 2-way per quarter.
// 256-B coalesced global reads, 128-B-run bf16x8 stores.
__global__ __launch_bounds__(256) void conv_w3(
    const float* __restrict__ Wi, const float* __restrict__ Ui,
    const float* __restrict__ Wf, const float* __restrict__ Uf,
    const float* __restrict__ Wg, const float* __restrict__ Ug,
    const float* __restrict__ Wo, const float* __restrict__ Uo,
    bf16* __restrict__ Bt) {
  __shared__ float tile[64 * 65];   // 16.25 KB
  const int bz = blockIdx.z;
  const int gate = bz >> 1, isU = bz & 1;
  const float* src;
  switch (bz) {
    case 0: src = Wi; break; case 1: src = Ui; break;
    case 2: src = Wf; break; case 3: src = Uf; break;
    case 4: src = Wg; break; case 5: src = Ug; break;
    default: src = (bz == 6) ? Wo : Uo; break;
  }
  const int k0 = blockIdx.x * 256, n0 = blockIdx.y * 64;
  const int t = threadIdx.x;
  const int c  = t & 15;        // float4 column (phase 1)
  const int kr = t >> 4;        // 0..15
  const int n2 = t >> 3;        // 0..31 (phase 2)
  const int u  = t & 7;         // k-chunk of 8 (phase 2)

  for (int s = 0; s < 4; ++s) {
    const int ks = k0 + s * 64;
    // phase 1: stage 64k x 64n fp32, coalesced rows -> scattered b32 LDS
#pragma unroll
    for (int ii = 0; ii < 4; ++ii) {
      const int kk = ii * 16 + kr;
      float4 v = *(const float4*)(src + (size_t)(ks + kk) * DH + n0 + c * 4);
      const float* vp = &v.x;
#pragma unroll
      for (int j = 0; j < 4; ++j) tile[(c * 4 + j) * 65 + kk] = vp[j];
    }
    __syncthreads();
    // phase 2: k-contig reads, convert, 16-B stores (128-B runs per 8 lanes)
#pragma unroll
    for (int jj = 0; jj < 2; ++jj) {
      const int nl = jj * 32 + n2;
      const float* p = &tile[nl * 65 + u * 8];
      bf16x8 o;
#pragma unroll
      for (int e = 0; e < 8; ++e) o[e] = (bf16)p[e];
      const int hc = n0 + nl;
      const size_t row = (size_t)((hc >> 4) * 64 + gate * 16 + (hc & 15));
      *(bf16x8*)(Bt + row * K + (size_t)(isU * DH + ks + 8 * u)) = o;
    }
    __syncthreads();
  }
}

// ------- kernel 3: fused GEMM + gates (BM=512, BN=64, 256 thr, 4 waves) ------
// LDS image is chunk-major: 1-KB blocks of [4 k-chunk][16 row][16 B].
// global_load_lds writes lane-linear, so lane l <-> (row=l&15, chunk=l>>4)
// on the SOURCE address produces exactly this image; fragment reads at
// quad*256 + lane15*16 hit banks 4*(lane15&7) per quarter-wave = conflict-free.
__device__ __forceinline__ float sigm(float x) { return 1.0f / (1.0f + __expf(-x)); }
__device__ __forceinline__ float tanh_(float x) { return 1.0f - 2.0f / (__expf(2.0f * x) + 1.0f); }

__global__ __launch_bounds__(256, 2) void lstm_gemm(
    const bf16* __restrict__ A, const bf16* __restrict__ Bt,
    const float* __restrict__ cp,
    const float* __restrict__ bi, const float* __restrict__ bfv,
    const float* __restrict__ bg, const float* __restrict__ bo,
    float* __restrict__ out) {
  __shared__ __align__(16) bf16 As[BM * BK];   // 32 KB: 32 x 1-KB chunk-major blocks
  __shared__ __align__(16) bf16 Bs[BN * BK];   // 4 KB:  4 x 1-KB blocks
  const int n0 = blockIdx.x * BN;              // Bt row base (gate-interleaved)
  const int m0 = blockIdx.y * BM;
  const int t = threadIdx.x, l = t & 63, w = t >> 6;
  const int lane15 = l & 15, quad = l >> 4;

  f32x4 acc[8][4];
#pragma unroll
  for (int i = 0; i < 8; ++i)
#pragma unroll
    for (int j = 0; j < 4; ++j) acc[i][j] = (f32x4)0.0f;

  for (int kt = 0; kt < K / BK; ++kt) {
    const int k0 = kt * BK;
    // A: 32 blocks of 16 rows; wave w stages blocks w*8..w*8+7.
    // lane l reads row (l&15), k-chunk (l>>4) -> LDS slot l*16 (chunk-major).
#pragma unroll
    for (int cc = 0; cc < 8; ++cc) {
      const int bb = w * 8 + cc;
      load_lds16(A + (size_t)(m0 + bb * 16 + lane15) * K + k0 + quad * 8,
                 (char*)As + bb * 1024);
    }
    // B: 4 blocks; wave w stages block w
    load_lds16(Bt + (size_t)(n0 + w * 16 + lane15) * K + k0 + quad * 8,
               (char*)Bs + w * 1024);
    __syncthreads();
    bf16x8 aF[8], bF[4];
#pragma unroll
    for (int i = 0; i < 8; ++i)
      aF[i] = *(const bf16x8*)((const char*)As + ((w * 8 + i) << 10) +
                               (quad << 8) + (lane15 << 4));
#pragma unroll
    for (int j = 0; j < 4; ++j)
      bF[j] = *(const bf16x8*)((const char*)Bs + (j << 10) +
                               (quad << 8) + (lane15 << 4));
#pragma unroll
    for (int i = 0; i < 8; ++i)
#pragma unroll
      for (int j = 0; j < 4; ++j)
        acc[i][j] = __builtin_amdgcn_mfma_f32_16x16x32_bf16(aF[i], bF[j], acc[i][j], 0, 0, 0);
    __syncthreads();
  }

  // Fused epilogue: lane's column j IS the gate (i,f,g,o); hc fixed per lane.
  const int hc = blockIdx.x * 16 + lane15;
  const float vbi = bi[hc], vbf = bfv[hc], vbg = bg[hc], vbo = bo[hc];
  float* outh = out;
  float* outc = out + (size_t)Bn * DH;
#pragma unroll
  for (int i = 0; i < 8; ++i) {
    const int brow = m0 + w * 128 + i * 16 + quad * 4;
#pragma unroll
    for (int r = 0; r < 4; ++r) {
      const int b = brow + r;
      const float zi = acc[i][0][r] + vbi;
      const float zf = acc[i][1][r] + vbf;
      const float zg = acc[i][2][r] + vbg;
      const float zo = acc[i][3][r] + vbo;
      const float ig = sigm(zi), fg = sigm(zf), gg = tanh_(zg), og = sigm(zo);
      const float cprev = cp[(size_t)b * DH + hc];
      const float cnew = fg * cprev + ig * gg;
      outh[(size_t)b * DH + hc] = og * tanh_(cnew);
      outc[(size_t)b * DH + hc] = cnew;
    }
  }
}

// ---------------- launch ----------------
extern "C" void kernel_launch(void* const* d_in, const int* in_sizes, int n_in,
                              void* d_out, int out_size, void* d_ws, size_t ws_size,
                              hipStream_t stream) {
  const float* x  = (const float*)d_in[0];
  const float* hp = (const float*)d_in[1];
  const float* cp = (const float*)d_in[2];
  const float* Wi = (const float*)d_in[3];
  const float* Ui = (const float*)d_in[4];
  const float* bi = (const float*)d_in[5];
  const float* Wf = (const float*)d_in[6];
  const float* Uf = (const float*)d_in[7];
  const float* bf = (const float*)d_in[8];
  const float* Wg = (const float*)d_in[9];
  const float* Ug = (const float*)d_in[10];
  const float* bg = (const float*)d_in[11];
  const float* Wo = (const float*)d_in[12];
  const float* Uo = (const float*)d_in[13];
  const float* bo = (const float*)d_in[14];

  // ws: A bf16 16 MB | Bt bf16 256 MB  (272 MB total)
  bf16* Aw = (bf16*)d_ws;
  bf16* Bt = (bf16*)((char*)d_ws + ((size_t)16 << 20));

  hipLaunchKernelGGL(conv_w3, dim3(16, 64, 8), dim3(256), 0, stream,
                     Wi, Ui, Wf, Uf, Wg, Ug, Wo, Uo, Bt);
  hipLaunchKernelGGL(pack_A, dim3((Bn * K / 4) / 256), dim3(256), 0, stream, x, hp, Aw);
  // grid = (N-blocks, M-blocks): the two M-blocks sharing a Bt slab are
  // 256 apart in linear id -> same XCD (id mod 8 equal) -> L2 reuse.
  hipLaunchKernelGGL(lstm_gemm, dim3((4 * DH) / BN, Bn / BM), dim3(256), 0, stream,
                     Aw, Bt, cp, bi, bf, bg, bo, (float*)d_out);
}

// Round 2
// 879.220 us; speedup vs baseline: 1.3000x; 1.3000x over previous
//
#include <hip/hip_runtime.h>
#include <cstdint>
#include <cstddef>

// LSTM cell: B=1024, D_IN=D_H=4096, fp32 in/out.
// z = [x|h] @ [[W],[U]] via bf16 MFMA. Bt[n'][k] gate-interleaved:
// n' = (hc>>4)*64 + gate*16 + (hc&15)  ->  per-block BN=64 slab holds all 4
// gates for 16 h-cols; GEMM epilogue computes gates/c/h in-register.
// Rev 2 lessons: chunk-major LDS image killed bank conflicts but broke
// adjacent-lane global coalescing (825 GB/s, +45% time). This rev keeps
// round-0's [row][chunk] image + 64-B-per-4-lane source runs and adds an
// XOR chunk swizzle (slot = chunk ^ ((row>>1)&3)): same 64-B run per 4
// lanes (permuted), fragment reads spread over all 8 bank groups.
// conv_w4: both prior convs ran ~1.5 TB/s regardless of LDS scheme ->
// bottleneck is 256-B reads at 16-KB stride. Now 256-n blocks = 1-KB
// contiguous read per k-row; padded bf16 LDS (132-B rows); 128-B writes.

typedef __bf16 bf16;
typedef __bf16 bf16x8 __attribute__((ext_vector_type(8)));
typedef __bf16 bf16x4 __attribute__((ext_vector_type(4)));
typedef float f32x4 __attribute__((ext_vector_type(4)));

static constexpr int Bn = 1024;   // batch
static constexpr int DH = 4096;
static constexpr int K  = 8192;   // 2*DH
static constexpr int BM = 512, BN = 64, BK = 32;

__device__ __forceinline__ void load_lds16(const void* g, void* l) {
  __builtin_amdgcn_global_load_lds(
      (const __attribute__((address_space(1))) unsigned int*)g,
      (__attribute__((address_space(3))) unsigned int*)l, 16, 0, 0);
}

// ---------------- kernel 1: pack A = [x | h_prev] -> bf16 [Bn][K] ------------
__global__ void pack_A(const float* __restrict__ x, const float* __restrict__ h,
                       bf16* __restrict__ A) {
  int idx4 = blockIdx.x * blockDim.x + threadIdx.x;   // one float4 position
  int b = idx4 >> 11;           // 2048 float4 per K-row
  int q = idx4 & 2047;
  int k = q << 2;
  const float* src = (k < DH) ? (x + (size_t)b * DH + k)
                              : (h + (size_t)b * DH + (k - DH));
  float4 v = *(const float4*)src;
  bf16x4 o;
  o[0] = (bf16)v.x; o[1] = (bf16)v.y; o[2] = (bf16)v.z; o[3] = (bf16)v.w;
  *(bf16x4*)(A + (size_t)idx4 * 4) = o;
}

// ---- kernel 2: transpose+convert weights -> gate-interleaved Bt[n'][k] ------
// Block tile 256k x 256n, 4 iters of [64k x 256n] through a padded bf16 LDS
// tile [256n][66 short] (132-B rows -> 1-dword bank rotation per row).
// Reads: 1 KB contiguous per k-row (64 lanes x float4).  Writes: 128-B runs.
// Phase-1 LDS writes are 8-way (accepted: ~30 us/CU, hidden under HBM).
__global__ __launch_bounds__(256) void conv_w4(
    const float* __restrict__ Wi, const float* __restrict__ Ui,
    const float* __restrict__ Wf, const float* __restrict__ Uf,
    const float* __restrict__ Wg, const float* __restrict__ Ug,
    const float* __restrict__ Wo, const float* __restrict__ Uo,
    bf16* __restrict__ Bt) {
  __shared__ short tile[256 * 66];   // 33 KB: [n_local][k pairs], stride 66
  const int bz = blockIdx.z;
  const int gate = bz >> 1, isU = bz & 1;
  const float* src;
  switch (bz) {
    case 0: src = Wi; break; case 1: src = Ui; break;
    case 2: src = Wf; break; case 3: src = Uf; break;
    case 4: src = Wg; break; case 5: src = Ug; break;
    default: src = (bz == 6) ? Wo : Uo; break;
  }
  const int kb = blockIdx.x * 256, n0 = blockIdx.y * 256;
  const int t = threadIdx.x;
  const int c  = t & 63;       // phase 1: n-quad column (256 n = 1 KB rows)
  const int rp = t >> 6;       // phase 1: wave id -> k-pair slot
  const int u  = t & 7;        // phase 2: 16-B chunk along k
  const int r2 = t >> 3;       // phase 2: n-row 0..31

  for (int it = 0; it < 4; ++it) {
    const int kt = kb + it * 64;
    // phase 1: read k-pair rows (1 KB/row), pack short2(k,k+1) per n
#pragma unroll
    for (int p = 0; p < 8; ++p) {
      const int kk = p * 4 + rp;            // pair index 0..31
      const int kl = 2 * kk;
      float4 v0 = *(const float4*)(src + (size_t)(kt + kl) * DH + n0 + c * 4);
      float4 v1 = *(const float4*)(src + (size_t)(kt + kl + 1) * DH + n0 + c * 4);
#pragma unroll
      for (int j = 0; j < 4; ++j) {
        bf16 lo = (bf16)((&v0.x)[j]);
        bf16 hi = (bf16)((&v1.x)[j]);
        short2 pk;
        pk.x = __builtin_bit_cast(short, lo);
        pk.y = __builtin_bit_cast(short, hi);
        *(short2*)&tile[(c * 4 + j) * 66 + kk * 2] = pk;
      }
    }
    __syncthreads();
    // phase 2: k-contig reads (4-B aligned b32s), 16-B stores, 128-B runs
#pragma unroll
    for (int p = 0; p < 8; ++p) {
      const int nl = p * 32 + r2;
      const int* pp = (const int*)&tile[nl * 66 + u * 8];
      int4 o;
      o.x = pp[0]; o.y = pp[1]; o.z = pp[2]; o.w = pp[3];
      const int hc = n0 + nl;
      const size_t row = (size_t)((hc >> 4) * 64 + gate * 16 + (hc & 15));
      *(int4*)(Bt + row * K + (size_t)(isU * DH + kt + 8 * u)) = o;
    }
    __syncthreads();
  }
}

// ------- kernel 3: fused GEMM + gates (BM=512, BN=64, 256 thr, 4 waves) ------
// LDS image [row][chunk-slot], slot = chunk ^ ((row>>1)&3).
// Staging: lane l -> row l>>2, slot l&3, global chunk (l&3)^((l>>3)&3):
// each 4-lane group covers one 64-B run (permuted) -> full coalescing.
// Fragment read: byte = row*64 + (quad ^ ((row>>1)&3))*16 -> per quarter-wave
// all 8 bank-groups x 2 lanes = conflict-free.
__device__ __forceinline__ float sigm(float x) { return 1.0f / (1.0f + __expf(-x)); }
__device__ __forceinline__ float tanh_(float x) { return 1.0f - 2.0f / (__expf(2.0f * x) + 1.0f); }

__global__ __launch_bounds__(256, 2) void lstm_gemm(
    const bf16* __restrict__ A, const bf16* __restrict__ Bt,
    const float* __restrict__ cp,
    const float* __restrict__ bi, const float* __restrict__ bfv,
    const float* __restrict__ bg, const float* __restrict__ bo,
    float* __restrict__ out) {
  __shared__ __align__(16) bf16 As[BM * BK];   // 32 KB: 32 x 1-KB blocks
  __shared__ __align__(16) bf16 Bs[BN * BK];   // 4 KB:  4 x 1-KB blocks
  const int n0 = blockIdx.x * BN;              // Bt row base (gate-interleaved)
  const int m0 = blockIdx.y * BM;
  const int t = threadIdx.x, l = t & 63, w = t >> 6;
  const int lane15 = l & 15, quad = l >> 4;
  const int srow = l >> 2;                     // staging row within 16-row block
  const int sg = (l & 3) ^ ((l >> 3) & 3);     // global k-chunk (XOR swizzle)
  const int fsw = quad ^ ((lane15 >> 1) & 3);  // fragment chunk slot

  f32x4 acc[8][4];
#pragma unroll
  for (int i = 0; i < 8; ++i)
#pragma unroll
    for (int j = 0; j < 4; ++j) acc[i][j] = (f32x4)0.0f;

  for (int kt = 0; kt < K / BK; ++kt) {
    const int k0 = kt * BK;
    // A: 32 blocks of 16 rows; wave w stages blocks w*8..w*8+7
#pragma unroll
    for (int cc = 0; cc < 8; ++cc) {
      const int bb = w * 8 + cc;
      load_lds16(A + (size_t)(m0 + bb * 16 + srow) * K + k0 + sg * 8,
                 (char*)As + bb * 1024);
    }
    // B: 4 blocks; wave w stages block w
    load_lds16(Bt + (size_t)(n0 + w * 16 + srow) * K + k0 + sg * 8,
               (char*)Bs + w * 1024);
    __syncthreads();
    bf16x8 aF[8], bF[4];
#pragma unroll
    for (int i = 0; i < 8; ++i)
      aF[i] = *(const bf16x8*)((const char*)As + ((w * 8 + i) << 10) +
                               (lane15 << 6) + (fsw << 4));
#pragma unroll
    for (int j = 0; j < 4; ++j)
      bF[j] = *(const bf16x8*)((const char*)Bs + (j << 10) +
                               (lane15 << 6) + (fsw << 4));
#pragma unroll
    for (int i = 0; i < 8; ++i)
#pragma unroll
      for (int j = 0; j < 4; ++j)
        acc[i][j] = __builtin_amdgcn_mfma_f32_16x16x32_bf16(aF[i], bF[j], acc[i][j], 0, 0, 0);
    __syncthreads();
  }

  // Fused epilogue: lane's column j IS the gate (i,f,g,o); hc fixed per lane.
  const int hc = blockIdx.x * 16 + lane15;
  const float vbi = bi[hc], vbf = bfv[hc], vbg = bg[hc], vbo = bo[hc];
  float* outh = out;
  float* outc = out + (size_t)Bn * DH;
#pragma unroll
  for (int i = 0; i < 8; ++i) {
    const int brow = m0 + w * 128 + i * 16 + quad * 4;
#pragma unroll
    for (int r = 0; r < 4; ++r) {
      const int b = brow + r;
      const float zi = acc[i][0][r] + vbi;
      const float zf = acc[i][1][r] + vbf;
      const float zg = acc[i][2][r] + vbg;
      const float zo = acc[i][3][r] + vbo;
      const float ig = sigm(zi), fg = sigm(zf), gg = tanh_(zg), og = sigm(zo);
      const float cprev = cp[(size_t)b * DH + hc];
      const float cnew = fg * cprev + ig * gg;
      outh[(size_t)b * DH + hc] = og * tanh_(cnew);
      outc[(size_t)b * DH + hc] = cnew;
    }
  }
}

// ---------------- launch ----------------
extern "C" void kernel_launch(void* const* d_in, const int* in_sizes, int n_in,
                              void* d_out, int out_size, void* d_ws, size_t ws_size,
                              hipStream_t stream) {
  const float* x  = (const float*)d_in[0];
  const float* hp = (const float*)d_in[1];
  const float* cp = (const float*)d_in[2];
  const float* Wi = (const float*)d_in[3];
  const float* Ui = (const float*)d_in[4];
  const float* bi = (const float*)d_in[5];
  const float* Wf = (const float*)d_in[6];
  const float* Uf = (const float*)d_in[7];
  const float* bf = (const float*)d_in[8];
  const float* Wg = (const float*)d_in[9];
  const float* Ug = (const float*)d_in[10];
  const float* bg = (const float*)d_in[11];
  const float* Wo = (const float*)d_in[12];
  const float* Uo = (const float*)d_in[13];
  const float* bo = (const float*)d_in[14];

  // ws: A bf16 16 MB | Bt bf16 256 MB  (272 MB total)
  bf16* Aw = (bf16*)d_ws;
  bf16* Bt = (bf16*)((char*)d_ws + ((size_t)16 << 20));

  hipLaunchKernelGGL(conv_w4, dim3(16, 16, 8), dim3(256), 0, stream,
                     Wi, Ui, Wf, Uf, Wg, Ug, Wo, Uo, Bt);
  hipLaunchKernelGGL(pack_A, dim3((Bn * K / 4) / 256), dim3(256), 0, stream, x, hp, Aw);
  // grid = (N-blocks, M-blocks): the two M-blocks sharing a Bt slab are
  // 256 apart in linear id -> same XCD (id mod 8 equal) -> L2 reuse.
  hipLaunchKernelGGL(lstm_gemm, dim3((4 * DH) / BN, Bn / BM), dim3(256), 0, stream,
                     Aw, Bt, cp, bi, bf, bg, bo, (float*)d_out);
}

// Round 3
// 800.607 us; speedup vs baseline: 1.4277x; 1.0982x over previous
//
#include <hip/hip_runtime.h>
#include <cstdint>
#include <cstddef>

// LSTM cell: B=1024, D_IN=D_H=4096, fp32 in/out.
// Rev 3: weight-transpose kernel ELIMINATED (was ~400-460 us at only ~1.8
// TB/s in every variant). The GEMM now reg-stages B directly from the fp32
// W/U matrices each K-step: coalesced 64-B reads -> cvt bf16 -> swizzled
// ds_write into the gate-interleaved LDS image. Weights stream once
// (512 MB fp32; both M-blocks co-resident so LLC dedups the 2nd read).
// K-loop is double-buffered (T3 minimum 2-phase): stage t+1 (B loads first,
// then A global_load_lds), compute t, write B t+1 late (T14 split).
// LDS image per 16-row block: [row][chunk-slot], slot = chunk ^ ((row>>1)&3)
// -> global_load_lds keeps 64-B/4-lane source runs, fragment ds_read_b128
// and staging ds_write_b32 both <=2-way banked (round-2: conflicts == 0).

typedef __bf16 bf16;
typedef __bf16 bf16x8 __attribute__((ext_vector_type(8)));
typedef __bf16 bf16x4 __attribute__((ext_vector_type(4)));
typedef float f32x4 __attribute__((ext_vector_type(4)));

static constexpr int Bn = 1024;   // batch
static constexpr int DH = 4096;
static constexpr int K  = 8192;   // 2*DH
static constexpr int BM = 512, BN = 64, BK = 32;
static constexpr int NT = K / BK;            // 256 K-steps
static constexpr int AS_SZ = BM * BK * 2;    // 32 KB per A buffer
static constexpr int BS_SZ = BN * BK * 2;    // 4 KB per B buffer
static constexpr int LDS_TOTAL = 2 * AS_SZ + 2 * BS_SZ;  // 72 KB

__device__ __forceinline__ void load_lds16(const void* g, void* l) {
  __builtin_amdgcn_global_load_lds(
      (const __attribute__((address_space(1))) unsigned int*)g,
      (__attribute__((address_space(3))) unsigned int*)l, 16, 0, 0);
}

// ---------------- kernel 1: pack A = [x | h_prev] -> bf16 [Bn][K] ------------
__global__ void pack_A(const float* __restrict__ x, const float* __restrict__ h,
                       bf16* __restrict__ A) {
  int idx4 = blockIdx.x * blockDim.x + threadIdx.x;   // one float4 position
  int b = idx4 >> 11;           // 2048 float4 per K-row
  int q = idx4 & 2047;
  int k = q << 2;
  const float* src = (k < DH) ? (x + (size_t)b * DH + k)
                              : (h + (size_t)b * DH + (k - DH));
  float4 v = *(const float4*)src;
  bf16x4 o;
  o[0] = (bf16)v.x; o[1] = (bf16)v.y; o[2] = (bf16)v.z; o[3] = (bf16)v.w;
  *(bf16x4*)(A + (size_t)idx4 * 4) = o;
}

// ---- kernel 2: fused GEMM + weight-transpose + gates ------------------------
// BM=512 x BN=64 (16 h-cols x 4 gates), 256 thr / 4 waves, 2 blocks/CU.
// Wave w owns gate w for B staging: lane l -> k-pair p=l>>2, col-quad cq=l&3;
// two float4 rows (k=2p, 2p+1) -> 4 short2 ds_writes at
//   byte = n'*64 + (chunk ^ ((n'>>1)&3))*16 + 4*(p&3),  n' = w*16+cq*4+j.
// Fragment reads use the matching slot: quad ^ ((lane15>>1)&3).
__device__ __forceinline__ float sigm(float x) { return 1.0f / (1.0f + __expf(-x)); }
__device__ __forceinline__ float tanh_(float x) { return 1.0f - 2.0f / (__expf(2.0f * x) + 1.0f); }

__global__ __launch_bounds__(256, 2) void lstm_fused(
    const bf16* __restrict__ A,
    const float* __restrict__ Wi, const float* __restrict__ Ui,
    const float* __restrict__ Wf, const float* __restrict__ Uf,
    const float* __restrict__ Wg, const float* __restrict__ Ug,
    const float* __restrict__ Wo, const float* __restrict__ Uo,
    const float* __restrict__ cp,
    const float* __restrict__ bi, const float* __restrict__ bfv,
    const float* __restrict__ bg, const float* __restrict__ bo,
    float* __restrict__ out) {
  extern __shared__ __align__(16) char lds[];
  const int m0 = blockIdx.y * BM;
  const int t = threadIdx.x, l = t & 63, w = t >> 6;
  const int lane15 = l & 15, quad = l >> 4;
  const int srow = l >> 2;                     // A staging row in 16-row block
  const int sg = (l & 3) ^ ((l >> 3) & 3);     // A global k-chunk (XOR swizzle)
  const int fsw = quad ^ ((lane15 >> 1) & 3);  // fragment chunk slot

  // B staging role: wave w = gate w
  const int p = l >> 2;        // k-pair 0..15
  const int cq = l & 3;        // col-quad 0..3
  const int hcol0 = blockIdx.x * 16;
  const float* baseW; const float* baseU;
  switch (w) {
    case 0: baseW = Wi; baseU = Ui; break;
    case 1: baseW = Wf; baseU = Uf; break;
    case 2: baseW = Wg; baseU = Ug; break;
    default: baseW = Wo; baseU = Uo; break;
  }
  baseW += hcol0 + cq * 4;
  baseU += hcol0 + cq * 4;

  f32x4 acc[8][4];
#pragma unroll
  for (int i = 0; i < 8; ++i)
#pragma unroll
    for (int j = 0; j < 4; ++j) acc[i][j] = (f32x4)0.0f;

  // ---- prologue: stage tile 0 into buffer 0 ----
  {
    const float* pb = baseW + (size_t)(2 * p) * DH;   // kt=0 -> W side
    float4 v0 = *(const float4*)pb;
    float4 v1 = *(const float4*)(pb + DH);
#pragma unroll
    for (int cc = 0; cc < 8; ++cc) {
      const int bb = w * 8 + cc;
      load_lds16(A + (size_t)(m0 + bb * 16 + srow) * K + sg * 8,
                 lds + bb * 1024);
    }
#pragma unroll
    for (int j = 0; j < 4; ++j) {
      const int np = w * 16 + cq * 4 + j;
      const int slot = (p >> 2) ^ ((np >> 1) & 3);
      short2 pk;
      pk.x = __builtin_bit_cast(short, (bf16)((&v0.x)[j]));
      pk.y = __builtin_bit_cast(short, (bf16)((&v1.x)[j]));
      *(short2*)(lds + 2 * AS_SZ + np * 64 + slot * 16 + 4 * (p & 3)) = pk;
    }
    __syncthreads();
  }

  for (int kt = 0; kt < NT; ++kt) {
    const int cur = kt & 1;
    char* As  = lds + cur * AS_SZ;
    char* Bs  = lds + 2 * AS_SZ + cur * BS_SZ;
    char* Asn = lds + (cur ^ 1) * AS_SZ;
    char* Bsn = lds + 2 * AS_SZ + (cur ^ 1) * BS_SZ;
    const bool hn = (kt + 1) < NT;
    float4 v0, v1;
    if (hn) {
      const int k0n = (kt + 1) * BK;
      const int kg = k0n + 2 * p;
      // whole step is on one side (BK | 4096), select per-lane is cheap
      const float* pb = (kg < DH) ? (baseW + (size_t)kg * DH)
                                  : (baseU + (size_t)(kg - DH) * DH);
      v0 = *(const float4*)pb;           // issue B loads first (T14)
      v1 = *(const float4*)(pb + DH);
#pragma unroll
      for (int cc = 0; cc < 8; ++cc) {   // then A direct-to-LDS
        const int bb = w * 8 + cc;
        load_lds16(A + (size_t)(m0 + bb * 16 + srow) * K + k0n + sg * 8,
                   Asn + bb * 1024);
      }
    }
    // compute current tile
    bf16x8 aF[8], bF[4];
#pragma unroll
    for (int i = 0; i < 8; ++i)
      aF[i] = *(const bf16x8*)(As + ((w * 8 + i) << 10) +
                               (lane15 << 6) + (fsw << 4));
#pragma unroll
    for (int j = 0; j < 4; ++j)
      bF[j] = *(const bf16x8*)(Bs + (j << 10) + (lane15 << 6) + (fsw << 4));
#pragma unroll
    for (int i = 0; i < 8; ++i)
#pragma unroll
      for (int j = 0; j < 4; ++j)
        acc[i][j] = __builtin_amdgcn_mfma_f32_16x16x32_bf16(aF[i], bF[j], acc[i][j], 0, 0, 0);
    if (hn) {
      // B write-late: cvt + swizzled ds_write into next buffer
#pragma unroll
      for (int j = 0; j < 4; ++j) {
        const int np = w * 16 + cq * 4 + j;
        const int slot = (p >> 2) ^ ((np >> 1) & 3);
        short2 pk;
        pk.x = __builtin_bit_cast(short, (bf16)((&v0.x)[j]));
        pk.y = __builtin_bit_cast(short, (bf16)((&v1.x)[j]));
        *(short2*)(Bsn + np * 64 + slot * 16 + 4 * (p & 3)) = pk;
      }
    }
    __syncthreads();
  }

  // Fused epilogue: lane's column j IS the gate (i,f,g,o); hc fixed per lane.
  const int hc = blockIdx.x * 16 + lane15;
  const float vbi = bi[hc], vbf = bfv[hc], vbg = bg[hc], vbo = bo[hc];
  float* outh = out;
  float* outc = out + (size_t)Bn * DH;
#pragma unroll
  for (int i = 0; i < 8; ++i) {
    const int brow = m0 + w * 128 + i * 16 + quad * 4;
#pragma unroll
    for (int r = 0; r < 4; ++r) {
      const int b = brow + r;
      const float zi = acc[i][0][r] + vbi;
      const float zf = acc[i][1][r] + vbf;
      const float zg = acc[i][2][r] + vbg;
      const float zo = acc[i][3][r] + vbo;
      const float ig = sigm(zi), fg = sigm(zf), gg = tanh_(zg), og = sigm(zo);
      const float cprev = cp[(size_t)b * DH + hc];
      const float cnew = fg * cprev + ig * gg;
      outh[(size_t)b * DH + hc] = og * tanh_(cnew);
      outc[(size_t)b * DH + hc] = cnew;
    }
  }
}

// ---------------- launch ----------------
extern "C" void kernel_launch(void* const* d_in, const int* in_sizes, int n_in,
                              void* d_out, int out_size, void* d_ws, size_t ws_size,
                              hipStream_t stream) {
  const float* x  = (const float*)d_in[0];
  const float* hp = (const float*)d_in[1];
  const float* cp = (const float*)d_in[2];
  const float* Wi = (const float*)d_in[3];
  const float* Ui = (const float*)d_in[4];
  const float* bi = (const float*)d_in[5];
  const float* Wf = (const float*)d_in[6];
  const float* Uf = (const float*)d_in[7];
  const float* bf = (const float*)d_in[8];
  const float* Wg = (const float*)d_in[9];
  const float* Ug = (const float*)d_in[10];
  const float* bg = (const float*)d_in[11];
  const float* Wo = (const float*)d_in[12];
  const float* Uo = (const float*)d_in[13];
  const float* bo = (const float*)d_in[14];

  // ws: A bf16 16 MB
  bf16* Aw = (bf16*)d_ws;

  static bool attr_set = false;
  if (!attr_set) {
    hipFuncSetAttribute((const void*)lstm_fused,
                        hipFuncAttributeMaxDynamicSharedMemorySize, LDS_TOTAL);
    attr_set = true;
  }

  hipLaunchKernelGGL(pack_A, dim3((Bn * K / 4) / 256), dim3(256), 0, stream, x, hp, Aw);
  hipLaunchKernelGGL(lstm_fused, dim3((4 * DH) / BN, Bn / BM), dim3(256),
                     LDS_TOTAL, stream,
                     Aw, Wi, Ui, Wf, Uf, Wg, Ug, Wo, Uo,
                     cp, bi, bf, bg, bo, (float*)d_out);
}